// Round 7
// baseline (1785.920 us; speedup 1.0000x reference)
//
#include <hip/hip_runtime.h>
#include <cstdint>

#define HD    128
#define QD    32          // dims per quarter; 64B bf16 rows, 3.2MB/quarter table
#define OUTD  10
#define NG    512
#define KSTEPS 10

typedef unsigned short ushort_t;
typedef unsigned int   uint_t;
typedef uint_t uint4v __attribute__((ext_vector_type(4)));   // native vec for nontemporal

// bf16 helpers (stored as ushort; f32 accumulate everywhere)
__device__ __forceinline__ float bf_lo(uint_t u) { return __uint_as_float(u << 16); }
__device__ __forceinline__ float bf_hi(uint_t u) { return __uint_as_float(u & 0xFFFF0000u); }
__device__ __forceinline__ uint_t f2bf_rne(float f) {
    uint_t u = __float_as_uint(f);
    return (u + 0x7FFFu + ((u >> 16) & 1u)) >> 16;
}
__device__ __forceinline__ uint_t pack_bf2(float lo, float hi) {
    return f2bf_rne(lo) | (f2bf_rne(hi) << 16);
}

// ---------------------------------------------------------------------------
// 1) Collapse the two linear layers: Wc = W1@W2, bc = b1@W2 + b2
// ---------------------------------------------------------------------------
__global__ void wc_kernel(const float* __restrict__ W1, const float* __restrict__ b1,
                          const float* __restrict__ W2, const float* __restrict__ b2,
                          float* __restrict__ Wc, float* __restrict__ bc) {
    int idx = blockIdx.x * 256 + threadIdx.x;      // 0..16383
    int d = idx >> 7, j = idx & 127;
    float s = 0.f;
    for (int t = 0; t < HD; t++) s += W1[d * HD + t] * W2[t * HD + j];
    Wc[idx] = s;
    if (idx < HD) {
        float sb = b2[idx];
        for (int t = 0; t < HD; t++) sb += b1[t] * W2[t * HD + idx];
        bc[idx] = sb;
    }
}

// ---------------------------------------------------------------------------
// 2) h[n][j] -> stored bf16 in quarter-major layout [4][N][32]
// ---------------------------------------------------------------------------
__global__ void __launch_bounds__(256) feat_kernel(
        const float* __restrict__ feat, const float* __restrict__ Wc,
        const float* __restrict__ bc, ushort_t* __restrict__ h, int N) {
    __shared__ float ftile[HD][16];
    int tid = threadIdx.x;
    int n0 = blockIdx.x * 16;
    #pragma unroll
    for (int r = 0; r < 8; r++) {
        int l = tid * 8 + r;
        int d = l >> 4, n = l & 15;
        int nn = n0 + n;
        ftile[d][n] = (nn < N) ? feat[(size_t)d * N + nn] : 0.f;
    }
    __syncthreads();
    int j = tid & 127, half = tid >> 7;
    float acc[8];
    #pragma unroll
    for (int i = 0; i < 8; i++) acc[i] = 0.f;
    for (int d = 0; d < HD; d++) {
        float w = Wc[d * HD + j];
        #pragma unroll
        for (int i = 0; i < 8; i++) acc[i] += ftile[d][half * 8 + i] * w;
    }
    float bb = bc[j];
    int q = j >> 5, r = j & 31;
    #pragma unroll
    for (int i = 0; i < 8; i++) {
        int n = n0 + half * 8 + i;
        if (n < N)
            h[((size_t)q * N + n) * QD + r] = (ushort_t)f2bf_rne(acc[i] + bb);
    }
}

// ---------------------------------------------------------------------------
// 3) CSR build (dst-sorted edge lists): count -> scan -> scatter
// ---------------------------------------------------------------------------
__global__ void count_kernel(const int* __restrict__ ei, int* __restrict__ cnt, int E) {
    int e = blockIdx.x * 256 + threadIdx.x;
    if (e < E) atomicAdd(&cnt[ei[E + e]], 1);       // dst row of edge_index
}

__global__ void scan_kernel(int* __restrict__ cnt, int* __restrict__ row_ptr,
                            int N, int E) {
    __shared__ int part[1024];
    int t = threadIdx.x;
    int chunk = (N + 1023) / 1024;
    int lo = t * chunk, hi = min(lo + chunk, N);
    int s = 0;
    for (int i = lo; i < hi; i++) s += cnt[i];
    part[t] = s;
    __syncthreads();
    for (int off = 1; off < 1024; off <<= 1) {
        int v = (t >= off) ? part[t - off] : 0;
        __syncthreads();
        part[t] += v;
        __syncthreads();
    }
    int run = (t == 0) ? 0 : part[t - 1];
    for (int i = lo; i < hi; i++) {
        int c = cnt[i];
        row_ptr[i] = run;
        cnt[i] = run;                                // cursor init
        run += c;
    }
    if (t == 1023) row_ptr[N] = E;
}

// Interleaved {src_as_float, weight} -> single 8B store per edge
__global__ void scatter_kernel(const int* __restrict__ ei, const float* __restrict__ ew_in,
                               int* __restrict__ cursor, float2* __restrict__ eswp, int E) {
    int e = blockIdx.x * 256 + threadIdx.x;
    if (e < E) {
        int d = ei[E + e];
        int p = atomicAdd(&cursor[d], 1);
        float2 v;
        v.x = __int_as_float(ei[e]);
        v.y = ew_in[e];
        eswp[p] = v;
    }
}

// ---------------------------------------------------------------------------
// 4) APPNP step, one QUARTER per launch (q is a kernel arg; 4 serial launches
//    per step force the 3.2MB quarter table L2-resident on every XCD).
//    Wave handles 4 nodes sequentially; per node: 16 edge-groups x 4 lanes,
//    one uint4 (8 bf16) per lane covers the 64B quarter-row.
//    Edge records + dst-write are non-temporal to keep L2 for x.
// ---------------------------------------------------------------------------
__global__ void __launch_bounds__(256) prop_kernel(
        const ushort_t* __restrict__ xs, ushort_t* __restrict__ xd,
        const ushort_t* __restrict__ h, const int* __restrict__ row_ptr,
        const float2* __restrict__ eswp, int N, int q) {
    int wid = threadIdx.x >> 6, lane = threadIdx.x & 63;
    const ushort_t* xq = xs + (size_t)q * N * QD;
    const ushort_t* hq = h  + (size_t)q * N * QD;
    ushort_t*       dq = xd + (size_t)q * N * QD;
    int grp = lane >> 2;        // edge slot 0..15
    int sub = lane & 3;         // dim slot: bf16 elems sub*8 .. sub*8+7

    int base_node = (blockIdx.x * 4 + wid) * 4;
    for (int nn = 0; nn < 4; nn++) {
        int node = base_node + nn;
        if (node >= N) return;
        int rs = row_ptr[node], re = row_ptr[node + 1];

        float acc[8];
        #pragma unroll
        for (int i = 0; i < 8; i++) acc[i] = 0.f;

        for (int base = rs; base < re; base += 16) {
            int e = base + grp;
            long long rec = 0;
            if (e < re)
                rec = __builtin_nontemporal_load((const long long*)eswp + e);
            int s   = (int)(uint_t)(rec & 0xFFFFFFFFll);
            float w = __uint_as_float((uint_t)((unsigned long long)rec >> 32));
            uint4 a = ((const uint4*)(xq + (size_t)s * QD))[sub];
            acc[0] += w * bf_lo(a.x); acc[1] += w * bf_hi(a.x);
            acc[2] += w * bf_lo(a.y); acc[3] += w * bf_hi(a.y);
            acc[4] += w * bf_lo(a.z); acc[5] += w * bf_hi(a.z);
            acc[6] += w * bf_lo(a.w); acc[7] += w * bf_hi(a.w);
        }

        // reduce over the 16 edge-groups -> lanes 0..3
        #pragma unroll
        for (int off = 32; off >= 4; off >>= 1) {
            #pragma unroll
            for (int i = 0; i < 8; i++) acc[i] += __shfl_down(acc[i], off);
        }

        if (grp == 0) {
            uint4 hv = ((const uint4*)(hq + (size_t)node * QD))[sub];
            float o0 = 0.9f * acc[0] + 0.1f * bf_lo(hv.x);
            float o1 = 0.9f * acc[1] + 0.1f * bf_hi(hv.x);
            float o2 = 0.9f * acc[2] + 0.1f * bf_lo(hv.y);
            float o3 = 0.9f * acc[3] + 0.1f * bf_hi(hv.y);
            float o4 = 0.9f * acc[4] + 0.1f * bf_lo(hv.z);
            float o5 = 0.9f * acc[5] + 0.1f * bf_hi(hv.z);
            float o6 = 0.9f * acc[6] + 0.1f * bf_lo(hv.w);
            float o7 = 0.9f * acc[7] + 0.1f * bf_hi(hv.w);
            uint4v ov;
            ov.x = pack_bf2(o0, o1);
            ov.y = pack_bf2(o2, o3);
            ov.z = pack_bf2(o4, o5);
            ov.w = pack_bf2(o6, o7);
            __builtin_nontemporal_store(ov, (uint4v*)(dq + (size_t)node * QD) + sub);
        }
    }
}

// ---------------------------------------------------------------------------
// 5) Pool (quarter-major x): batch sorted -> running accumulator.
// ---------------------------------------------------------------------------
#define POOL_CHUNK 128
__global__ void pool_kernel(const ushort_t* __restrict__ x, const int* __restrict__ batch,
                            float* __restrict__ pooled, int N) {
    int j = threadIdx.x;
    int q = j >> 5, r = j & 31;
    const ushort_t* xq = x + (size_t)q * N * QD;
    int n0 = blockIdx.x * POOL_CHUNK;
    if (n0 >= N) return;
    int n1 = min(n0 + POOL_CHUNK, N);
    int cur = batch[n0];
    float acc = 0.f;
    for (int n = n0; n < n1; n++) {
        int g = batch[n];
        if (g != cur) {
            atomicAdd(&pooled[cur * HD + j], acc);
            acc = 0.f; cur = g;
        }
        acc += __uint_as_float(((uint_t)xq[(size_t)n * QD + r]) << 16);
    }
    atomicAdd(&pooled[cur * HD + j], acc);
}

// ---------------------------------------------------------------------------
// 6) Head: y = log_softmax(relu(pooled@V0w+V0b) @ V1w + V1b). Block per graph.
// ---------------------------------------------------------------------------
__global__ void head_kernel(const float* __restrict__ pooled, const float* __restrict__ V0w,
                            const float* __restrict__ V0b, const float* __restrict__ V1w,
                            const float* __restrict__ V1b, float* __restrict__ out) {
    __shared__ float prow[HD];
    __shared__ float y1[HD];
    __shared__ float y2[OUTD];
    __shared__ float lse;
    int g = blockIdx.x, j = threadIdx.x;
    prow[j] = pooled[g * HD + j];
    __syncthreads();
    float a = V0b[j];
    for (int d = 0; d < HD; d++) a += prow[d] * V0w[d * HD + j];
    y1[j] = a > 0.f ? a : 0.f;
    __syncthreads();
    if (j < OUTD) {
        float a2 = V1b[j];
        for (int t = 0; t < HD; t++) a2 += y1[t] * V1w[t * OUTD + j];
        y2[j] = a2;
    }
    __syncthreads();
    if (j == 0) {
        float m = y2[0];
        for (int o = 1; o < OUTD; o++) m = fmaxf(m, y2[o]);
        float s = 0.f;
        for (int o = 0; o < OUTD; o++) s += expf(y2[o] - m);
        lse = m + logf(s);
    }
    __syncthreads();
    if (j < OUTD) out[g * OUTD + j] = y2[j] - lse;
}

// ---------------------------------------------------------------------------
extern "C" void kernel_launch(void* const* d_in, const int* in_sizes, int n_in,
                              void* d_out, int out_size, void* d_ws, size_t ws_size,
                              hipStream_t stream) {
    const float* feat = (const float*)d_in[0];
    const float* ewt  = (const float*)d_in[1];
    const float* W1   = (const float*)d_in[2];
    const float* b1   = (const float*)d_in[3];
    const float* W2   = (const float*)d_in[4];
    const float* b2   = (const float*)d_in[5];
    const float* V0w  = (const float*)d_in[6];
    const float* V0b  = (const float*)d_in[7];
    const float* V1w  = (const float*)d_in[8];
    const float* V1b  = (const float*)d_in[9];
    const int*   ei   = (const int*)d_in[10];
    const int*   batch= (const int*)d_in[11];
    const int E = in_sizes[1];
    const int N = in_sizes[11];
    float* out = (float*)d_out;

    char* ws = (char*)d_ws;
    size_t off = 0;
    auto alloc = [&](size_t bytes) -> char* {
        char* p = ws + off;
        off = (off + bytes + 255) & ~(size_t)255;
        return p;
    };
    float*    Wc     = (float*)alloc((size_t)HD * HD * 4);
    float*    bc     = (float*)alloc((size_t)HD * 4);
    ushort_t* hb     = (ushort_t*)alloc((size_t)N * HD * 2);
    ushort_t* xA     = (ushort_t*)alloc((size_t)N * HD * 2);
    ushort_t* xB     = (ushort_t*)alloc((size_t)N * HD * 2);
    float*    pooled = (float*)alloc((size_t)NG * HD * 4);
    int*      row_ptr= (int*)alloc((size_t)(N + 1) * 4);
    int*      cnt    = (int*)alloc((size_t)N * 4);
    float2*   eswp   = (float2*)alloc((size_t)E * 8);
    (void)ws_size;

    (void)hipMemsetAsync(cnt, 0, (size_t)N * 4, stream);
    (void)hipMemsetAsync(pooled, 0, (size_t)NG * HD * 4, stream);

    wc_kernel<<<64, 256, 0, stream>>>(W1, b1, W2, b2, Wc, bc);
    feat_kernel<<<(N + 15) / 16, 256, 0, stream>>>(feat, Wc, bc, hb, N);
    count_kernel<<<(E + 255) / 256, 256, 0, stream>>>(ei, cnt, E);
    scan_kernel<<<1, 1024, 0, stream>>>(cnt, row_ptr, N, E);
    scatter_kernel<<<(E + 255) / 256, 256, 0, stream>>>(ei, ewt, cnt, eswp, E);

    const ushort_t* src = hb;
    ushort_t* dst = xA;
    int nb = (N + 15) / 16;
    for (int k = 0; k < KSTEPS; k++) {
        for (int q = 0; q < 4; q++)
            prop_kernel<<<nb, 256, 0, stream>>>(src, dst, hb, row_ptr, eswp, N, q);
        src = dst;
        dst = (dst == xA) ? xB : xA;
    }

    pool_kernel<<<(N + POOL_CHUNK - 1) / POOL_CHUNK, HD, 0, stream>>>(src, batch, pooled, N);
    head_kernel<<<NG, HD, 0, stream>>>(pooled, V0w, V0b, V1w, V1b, out);
}

// Round 8
// 980.085 us; speedup vs baseline: 1.8222x; 1.8222x over previous
//
#include <hip/hip_runtime.h>
#include <cstdint>

#define HD    128
#define OUTD  10
#define NG    512
#define KSTEPS 10

typedef unsigned short ushort_t;
typedef unsigned int   uint_t;

// bf16 helpers (stored as ushort; f32 accumulate everywhere)
__device__ __forceinline__ float bf_lo(uint_t u) { return __uint_as_float(u << 16); }
__device__ __forceinline__ float bf_hi(uint_t u) { return __uint_as_float(u & 0xFFFF0000u); }
__device__ __forceinline__ uint_t f2bf_rne(float f) {
    uint_t u = __float_as_uint(f);
    return (u + 0x7FFFu + ((u >> 16) & 1u)) >> 16;
}
__device__ __forceinline__ uint_t pack_bf2(float lo, float hi) {
    return f2bf_rne(lo) | (f2bf_rne(hi) << 16);
}

// Packed edge record: low 16 bits = src node (N=50000 < 65536),
// high 16 bits = bf16(weight) (weights in [0,1) -> sign bit 0).
__device__ __forceinline__ uint_t pack_edge(int src, float w) {
    return (uint_t)src | (f2bf_rne(w) << 16);
}

// ---------------------------------------------------------------------------
// 1) Collapse the two linear layers: Wc = W1@W2, bc = b1@W2 + b2
// ---------------------------------------------------------------------------
__global__ void wc_kernel(const float* __restrict__ W1, const float* __restrict__ b1,
                          const float* __restrict__ W2, const float* __restrict__ b2,
                          float* __restrict__ Wc, float* __restrict__ bc) {
    int idx = blockIdx.x * 256 + threadIdx.x;      // 0..16383
    int d = idx >> 7, j = idx & 127;
    float s = 0.f;
    for (int t = 0; t < HD; t++) s += W1[d * HD + t] * W2[t * HD + j];
    Wc[idx] = s;
    if (idx < HD) {
        float sb = b2[idx];
        for (int t = 0; t < HD; t++) sb += b1[t] * W2[t * HD + idx];
        bc[idx] = sb;
    }
}

// ---------------------------------------------------------------------------
// 2) h[n][j] = sum_d feat[d][n] * Wc[d][j] + bc[j]  -> stored bf16 [N][128]
// ---------------------------------------------------------------------------
__global__ void __launch_bounds__(256) feat_kernel(
        const float* __restrict__ feat, const float* __restrict__ Wc,
        const float* __restrict__ bc, ushort_t* __restrict__ h, int N) {
    __shared__ float ftile[HD][16];
    int tid = threadIdx.x;
    int n0 = blockIdx.x * 16;
    #pragma unroll
    for (int r = 0; r < 8; r++) {
        int l = tid * 8 + r;
        int d = l >> 4, n = l & 15;
        int nn = n0 + n;
        ftile[d][n] = (nn < N) ? feat[(size_t)d * N + nn] : 0.f;
    }
    __syncthreads();
    int j = tid & 127, half = tid >> 7;
    float acc[8];
    #pragma unroll
    for (int i = 0; i < 8; i++) acc[i] = 0.f;
    for (int d = 0; d < HD; d++) {
        float w = Wc[d * HD + j];
        #pragma unroll
        for (int i = 0; i < 8; i++) acc[i] += ftile[d][half * 8 + i] * w;
    }
    float bb = bc[j];
    #pragma unroll
    for (int i = 0; i < 8; i++) {
        int n = n0 + half * 8 + i;
        if (n < N) h[(size_t)n * HD + j] = (ushort_t)f2bf_rne(acc[i] + bb);
    }
}

// ---------------------------------------------------------------------------
// 3) CSR build (dst-sorted edge lists): count -> scan -> scatter
// ---------------------------------------------------------------------------
__global__ void count_kernel(const int* __restrict__ ei, int* __restrict__ cnt, int E) {
    int e = blockIdx.x * 256 + threadIdx.x;
    if (e < E) atomicAdd(&cnt[ei[E + e]], 1);       // dst row of edge_index
}

__global__ void scan_kernel(int* __restrict__ cnt, int* __restrict__ row_ptr,
                            int N, int E) {
    __shared__ int part[1024];
    int t = threadIdx.x;
    int chunk = (N + 1023) / 1024;
    int lo = t * chunk, hi = min(lo + chunk, N);
    int s = 0;
    for (int i = lo; i < hi; i++) s += cnt[i];
    part[t] = s;
    __syncthreads();
    for (int off = 1; off < 1024; off <<= 1) {
        int v = (t >= off) ? part[t - off] : 0;
        __syncthreads();
        part[t] += v;
        __syncthreads();
    }
    int run = (t == 0) ? 0 : part[t - 1];
    for (int i = lo; i < hi; i++) {
        int c = cnt[i];
        row_ptr[i] = run;
        cnt[i] = run;                                // cursor init
        run += c;
    }
    if (t == 1023) row_ptr[N] = E;
}

// 4B packed record {src16 | bf16w} -> single 4B store per edge
__global__ void scatter_kernel(const int* __restrict__ ei, const float* __restrict__ ew_in,
                               int* __restrict__ cursor, uint_t* __restrict__ epk, int E) {
    int e = blockIdx.x * 256 + threadIdx.x;
    if (e < E) {
        int d = ei[E + e];
        int p = atomicAdd(&cursor[d], 1);
        epk[p] = pack_edge(ei[e], ew_in[e]);
    }
}

// ---------------------------------------------------------------------------
// 4) APPNP step (bf16 rows [N][128]) — R3 structure (best measured):
//    wave per dst node; 4 edge-groups x 16 lanes; each group owns one edge
//    and reads the 256B source row coalesced (one uint4 of 8 bf16 per lane).
//    2x unroll -> 8 edges per iteration. f32 accumulate, bf16-RNE out.
// ---------------------------------------------------------------------------
__global__ void __launch_bounds__(256) prop_kernel(
        const ushort_t* __restrict__ xs, ushort_t* __restrict__ xd,
        const ushort_t* __restrict__ h, const int* __restrict__ row_ptr,
        const uint_t* __restrict__ epk, int N) {
    int wid = threadIdx.x >> 6, lane = threadIdx.x & 63;
    int node = blockIdx.x * 4 + wid;
    if (node >= N) return;
    int rs = row_ptr[node], re = row_ptr[node + 1];
    int grp = lane >> 4;        // edge slot 0..3
    int sub = lane & 15;        // dim slot: bf16 elems sub*8 .. sub*8+7

    float acc[8];
    #pragma unroll
    for (int i = 0; i < 8; i++) acc[i] = 0.f;

    for (int base = rs; base < re; base += 8) {
        int e0 = base + grp, e1 = base + grp + 4;
        uint_t r0 = (e0 < re) ? epk[e0] : 0u;
        uint_t r1 = (e1 < re) ? epk[e1] : 0u;
        int s0 = (int)(r0 & 0xFFFFu);
        int s1 = (int)(r1 & 0xFFFFu);
        float w0 = __uint_as_float(r0 & 0xFFFF0000u);
        float w1 = __uint_as_float(r1 & 0xFFFF0000u);
        uint4 a = ((const uint4*)(xs + (size_t)s0 * HD))[sub];
        uint4 b = ((const uint4*)(xs + (size_t)s1 * HD))[sub];

        acc[0] += w0 * bf_lo(a.x); acc[1] += w0 * bf_hi(a.x);
        acc[2] += w0 * bf_lo(a.y); acc[3] += w0 * bf_hi(a.y);
        acc[4] += w0 * bf_lo(a.z); acc[5] += w0 * bf_hi(a.z);
        acc[6] += w0 * bf_lo(a.w); acc[7] += w0 * bf_hi(a.w);
        acc[0] += w1 * bf_lo(b.x); acc[1] += w1 * bf_hi(b.x);
        acc[2] += w1 * bf_lo(b.y); acc[3] += w1 * bf_hi(b.y);
        acc[4] += w1 * bf_lo(b.z); acc[5] += w1 * bf_hi(b.z);
        acc[6] += w1 * bf_lo(b.w); acc[7] += w1 * bf_hi(b.w);
    }

    // reduce across the 4 edge groups
    #pragma unroll
    for (int off = 32; off >= 16; off >>= 1) {
        #pragma unroll
        for (int i = 0; i < 8; i++) acc[i] += __shfl_down(acc[i], off);
    }

    if (grp == 0) {
        uint4 hv = ((const uint4*)(h + (size_t)node * HD))[sub];
        float o0 = 0.9f * acc[0] + 0.1f * bf_lo(hv.x);
        float o1 = 0.9f * acc[1] + 0.1f * bf_hi(hv.x);
        float o2 = 0.9f * acc[2] + 0.1f * bf_lo(hv.y);
        float o3 = 0.9f * acc[3] + 0.1f * bf_hi(hv.y);
        float o4 = 0.9f * acc[4] + 0.1f * bf_lo(hv.z);
        float o5 = 0.9f * acc[5] + 0.1f * bf_hi(hv.z);
        float o6 = 0.9f * acc[6] + 0.1f * bf_lo(hv.w);
        float o7 = 0.9f * acc[7] + 0.1f * bf_hi(hv.w);
        uint4 ov;
        ov.x = pack_bf2(o0, o1);
        ov.y = pack_bf2(o2, o3);
        ov.z = pack_bf2(o4, o5);
        ov.w = pack_bf2(o6, o7);
        ((uint4*)(xd + (size_t)node * HD))[sub] = ov;
    }
}

// ---------------------------------------------------------------------------
// 5) Pool: batch is sorted -> running accumulator, atomic only on boundary.
// ---------------------------------------------------------------------------
#define POOL_CHUNK 128
__global__ void pool_kernel(const ushort_t* __restrict__ x, const int* __restrict__ batch,
                            float* __restrict__ pooled, int N) {
    int j = threadIdx.x;
    int n0 = blockIdx.x * POOL_CHUNK;
    if (n0 >= N) return;
    int n1 = min(n0 + POOL_CHUNK, N);
    int cur = batch[n0];
    float acc = 0.f;
    for (int n = n0; n < n1; n++) {
        int g = batch[n];
        if (g != cur) {
            atomicAdd(&pooled[cur * HD + j], acc);
            acc = 0.f; cur = g;
        }
        acc += __uint_as_float(((uint_t)x[(size_t)n * HD + j]) << 16);
    }
    atomicAdd(&pooled[cur * HD + j], acc);
}

// ---------------------------------------------------------------------------
// 6) Head: y = log_softmax(relu(pooled@V0w+V0b) @ V1w + V1b). Block per graph.
// ---------------------------------------------------------------------------
__global__ void head_kernel(const float* __restrict__ pooled, const float* __restrict__ V0w,
                            const float* __restrict__ V0b, const float* __restrict__ V1w,
                            const float* __restrict__ V1b, float* __restrict__ out) {
    __shared__ float prow[HD];
    __shared__ float y1[HD];
    __shared__ float y2[OUTD];
    __shared__ float lse;
    int g = blockIdx.x, j = threadIdx.x;
    prow[j] = pooled[g * HD + j];
    __syncthreads();
    float a = V0b[j];
    for (int d = 0; d < HD; d++) a += prow[d] * V0w[d * HD + j];
    y1[j] = a > 0.f ? a : 0.f;
    __syncthreads();
    if (j < OUTD) {
        float a2 = V1b[j];
        for (int t = 0; t < HD; t++) a2 += y1[t] * V1w[t * OUTD + j];
        y2[j] = a2;
    }
    __syncthreads();
    if (j == 0) {
        float m = y2[0];
        for (int o = 1; o < OUTD; o++) m = fmaxf(m, y2[o]);
        float s = 0.f;
        for (int o = 0; o < OUTD; o++) s += expf(y2[o] - m);
        lse = m + logf(s);
    }
    __syncthreads();
    if (j < OUTD) out[g * OUTD + j] = y2[j] - lse;
}

// ---------------------------------------------------------------------------
extern "C" void kernel_launch(void* const* d_in, const int* in_sizes, int n_in,
                              void* d_out, int out_size, void* d_ws, size_t ws_size,
                              hipStream_t stream) {
    const float* feat = (const float*)d_in[0];
    const float* ewt  = (const float*)d_in[1];
    const float* W1   = (const float*)d_in[2];
    const float* b1   = (const float*)d_in[3];
    const float* W2   = (const float*)d_in[4];
    const float* b2   = (const float*)d_in[5];
    const float* V0w  = (const float*)d_in[6];
    const float* V0b  = (const float*)d_in[7];
    const float* V1w  = (const float*)d_in[8];
    const float* V1b  = (const float*)d_in[9];
    const int*   ei   = (const int*)d_in[10];
    const int*   batch= (const int*)d_in[11];
    const int E = in_sizes[1];
    const int N = in_sizes[11];
    float* out = (float*)d_out;

    char* ws = (char*)d_ws;
    size_t off = 0;
    auto alloc = [&](size_t bytes) -> char* {
        char* p = ws + off;
        off = (off + bytes + 255) & ~(size_t)255;
        return p;
    };
    float*    Wc     = (float*)alloc((size_t)HD * HD * 4);
    float*    bc     = (float*)alloc((size_t)HD * 4);
    ushort_t* hb     = (ushort_t*)alloc((size_t)N * HD * 2);
    ushort_t* xA     = (ushort_t*)alloc((size_t)N * HD * 2);
    ushort_t* xB     = (ushort_t*)alloc((size_t)N * HD * 2);
    float*    pooled = (float*)alloc((size_t)NG * HD * 4);
    int*      row_ptr= (int*)alloc((size_t)(N + 1) * 4);
    int*      cnt    = (int*)alloc((size_t)N * 4);
    uint_t*   epk    = (uint_t*)alloc((size_t)E * 4);
    (void)ws_size;

    (void)hipMemsetAsync(cnt, 0, (size_t)N * 4, stream);
    (void)hipMemsetAsync(pooled, 0, (size_t)NG * HD * 4, stream);

    wc_kernel<<<64, 256, 0, stream>>>(W1, b1, W2, b2, Wc, bc);
    feat_kernel<<<(N + 15) / 16, 256, 0, stream>>>(feat, Wc, bc, hb, N);
    count_kernel<<<(E + 255) / 256, 256, 0, stream>>>(ei, cnt, E);
    scan_kernel<<<1, 1024, 0, stream>>>(cnt, row_ptr, N, E);
    scatter_kernel<<<(E + 255) / 256, 256, 0, stream>>>(ei, ewt, cnt, epk, E);

    const ushort_t* src = hb;
    ushort_t* dst = xA;
    for (int k = 0; k < KSTEPS; k++) {
        prop_kernel<<<(N + 3) / 4, 256, 0, stream>>>(src, dst, hb, row_ptr, epk, N);
        src = dst;
        dst = (dst == xA) ? xB : xA;
    }

    pool_kernel<<<(N + POOL_CHUNK - 1) / POOL_CHUNK, HD, 0, stream>>>(src, batch, pooled, N);
    head_kernel<<<NG, HD, 0, stream>>>(pooled, V0w, V0b, V1w, V1b, out);
}